// Round 11
// baseline (536.047 us; speedup 1.0000x reference)
//
#include <hip/hip_runtime.h>
#include <hip/hip_bf16.h>
#include <hip/hip_fp16.h>
#include <math.h>

#define N_NODES 50000
#define N_EDGES 800000
#define M_EDGES (N_EDGES + N_NODES)
#define NGRAPH 512

typedef __attribute__((ext_vector_type(8))) short bfrag8;
typedef __attribute__((ext_vector_type(4))) float floatx4;

__device__ __forceinline__ float wave_max(float v){
  #pragma unroll
  for (int o = 32; o; o >>= 1) v = fmaxf(v, __shfl_xor(v, o));
  return v;
}
__device__ __forceinline__ float wave_sum(float v){
  #pragma unroll
  for (int o = 32; o; o >>= 1) v += __shfl_xor(v, o);
  return v;
}
__device__ __forceinline__ unsigned short f2bf(float f){
  union { float f; unsigned int u; } v; v.f = f;
  unsigned int r = v.u + 0x7FFFu + ((v.u >> 16) & 1u);
  return (unsigned short)(r >> 16);
}
__device__ __forceinline__ float bf2f(unsigned short h){
  union { unsigned int u; float f; } v; v.u = ((unsigned int)h) << 16; return v.f;
}

// ---- fused prep: edge-count + W1/W2 split panels + P projection ------------
// blocks [0,3321): count; [3321,3577): W1 col; [3577,3641): W2 col; [3641]: projP
#define NB_COUNT 3321
__global__ __launch_bounds__(256) void k_prepc(const int* __restrict__ ei,
                                               const float* __restrict__ W1,
                                               const float* __restrict__ W2,
                                               const float* __restrict__ as1,
                                               const float* __restrict__ ad1,
                                               int* __restrict__ deg,
                                               unsigned short* __restrict__ W1B3t,
                                               unsigned short* __restrict__ W2B3t,
                                               float* __restrict__ P){
  const int b = blockIdx.x, tid = threadIdx.x;
  if (b < NB_COUNT){
    int e = b * 256 + tid;
    if (e < M_EDGES){
      int dst = (e < N_EDGES) ? ei[N_EDGES + e] : (e - N_EDGES);
      atomicAdd(&deg[dst], 1);
    }
  } else if (b < NB_COUNT + 256){
    const int n = b - NB_COUNT;
    #pragma unroll
    for (int p = 0; p < 3; ++p){
      const int k = p * 256 + tid;
      float w = W1[(size_t)(k & 255) * 256 + n];
      unsigned short hi = f2bf(w);
      W1B3t[(size_t)n * 768 + k] = (k < 512) ? hi : f2bf(w - bf2f(hi));
    }
  } else if (b < NB_COUNT + 320){
    const int n = b - (NB_COUNT + 256);
    #pragma unroll
    for (int p = 0; p < 3; ++p){
      const int k = p * 256 + tid;
      float w = W2[(size_t)(k & 255) * 64 + n];
      unsigned short hi = f2bf(w);
      W2B3t[(size_t)n * 768 + k] = (k < 512) ? hi : f2bf(w - bf2f(hi));
    }
  } else {
    const int k = tid;
    float acc[8] = {0.f,0.f,0.f,0.f,0.f,0.f,0.f,0.f};
    for (int c = 0; c < 64; ++c){
      #pragma unroll
      for (int h = 0; h < 4; ++h){
        float w = W1[k * 256 + h * 64 + c];
        acc[h]     += w * as1[h * 64 + c];
        acc[4 + h] += w * ad1[h * 64 + c];
      }
    }
    #pragma unroll
    for (int j = 0; j < 8; ++j) P[k * 8 + j] = acc[j];
  }
}

// --- fused: att1 scalars + x->split-bf16 x2 (12500 blocks) + CSR scan (1) ---
__global__ __launch_bounds__(256) void k_att1s(const float* __restrict__ x,
                                               const float* __restrict__ P,
                                               float* __restrict__ asrc,
                                               float* __restrict__ adst,
                                               unsigned short* __restrict__ x2,
                                               const int* __restrict__ deg,
                                               int* __restrict__ row_start){
  __shared__ float Ps[256][9];
  __shared__ int wsum[4];
  const int tid = threadIdx.x;
  const int wv = tid >> 6, lane = tid & 63;
  if (blockIdx.x < 12500){
    #pragma unroll
    for (int j = 0; j < 8; ++j) Ps[tid][j] = P[tid * 8 + j];
    __syncthreads();
    const int n = blockIdx.x * 4 + wv;
    float4 xv = *(const float4*)&x[(size_t)n * 256 + lane * 4];
    ushort4 hi4, lo4;
    hi4.x = f2bf(xv.x); lo4.x = f2bf(xv.x - bf2f(hi4.x));
    hi4.y = f2bf(xv.y); lo4.y = f2bf(xv.y - bf2f(hi4.y));
    hi4.z = f2bf(xv.z); lo4.z = f2bf(xv.z - bf2f(hi4.z));
    hi4.w = f2bf(xv.w); lo4.w = f2bf(xv.w - bf2f(hi4.w));
    *(ushort4*)&x2[(size_t)n * 512 + lane * 4] = hi4;
    *(ushort4*)&x2[(size_t)n * 512 + 256 + lane * 4] = lo4;
    float p[8];
    #pragma unroll
    for (int j = 0; j < 8; ++j){
      p[j] = xv.x * Ps[lane * 4 + 0][j] + xv.y * Ps[lane * 4 + 1][j]
           + xv.z * Ps[lane * 4 + 2][j] + xv.w * Ps[lane * 4 + 3][j];
      p[j] = wave_sum(p[j]);
    }
    if (lane == 0){
      *(float4*)&asrc[n * 4] = make_float4(p[0], p[1], p[2], p[3]);
      *(float4*)&adst[n * 4] = make_float4(p[4], p[5], p[6], p[7]);
    }
  } else {
    // two-phase exclusive prefix scan: deg -> row_start
    const int CH = 196;                 // 196*256 = 50176 >= N_NODES
    const int beg = tid * CH;
    const int end = min(beg + CH, N_NODES);
    int tot = 0;
    for (int i = beg; i < end; ++i) tot += deg[i];
    int xs = tot;
    #pragma unroll
    for (int o = 1; o < 64; o <<= 1){
      int t = __shfl_up(xs, o);
      if (lane >= o) xs += t;
    }
    if (lane == 63) wsum[wv] = xs;
    __syncthreads();
    int off = 0;
    for (int k = 0; k < wv; ++k) off += wsum[k];
    int run = off + xs - tot;
    for (int i = beg; i < end; ++i){ row_start[i] = run; run += deg[i]; }
  }
}

// ---- fused: split-bf16 MFMA GEMM1 (BM=128,BN=128) + CSR fill ---------------
// blocks [0,782): gemm (bx = b&1, by = b>>1); [782, 782+3321): fill
__global__ __launch_bounds__(256) void k_fg1(const unsigned short* __restrict__ A,
                                             const unsigned short* __restrict__ Bt,
                                             __half* __restrict__ C,
                                             const int* __restrict__ ei,
                                             const int* __restrict__ row_start,
                                             int* __restrict__ fill,
                                             int* __restrict__ col){
  __shared__ unsigned short As[128 * 64];
  __shared__ unsigned short Bs[128 * 64];
  const int tid = threadIdx.x;
  if (blockIdx.x >= 782){
    int e = (blockIdx.x - 782) * 256 + tid;
    if (e < M_EDGES){
      int src, dst;
      if (e < N_EDGES){ src = ei[e]; dst = ei[N_EDGES + e]; }
      else { src = dst = e - N_EDGES; }
      int slot = row_start[dst] + atomicAdd(&fill[dst], 1);
      col[slot] = src;
    }
    return;
  }
  const int m0 = (blockIdx.x >> 1) * 128, n0 = (blockIdx.x & 1) * 128;
  floatx4 acc[4][4];
  #pragma unroll
  for (int mr = 0; mr < 4; ++mr)
    #pragma unroll
    for (int nr = 0; nr < 4; ++nr) acc[mr][nr] = (floatx4){0.f, 0.f, 0.f, 0.f};
  const int l = tid & 63, w = tid >> 6;
  const int wm = (w >> 1) * 64, wn = (w & 1) * 64;
  const int lr = l & 15;

  for (int kc = 0; kc < 768; kc += 64){
    #pragma unroll
    for (int i = 0; i < 4; ++i){
      int f = tid + i * 256, row = f >> 3, seg = f & 7;
      int sseg = seg ^ (row & 7);
      float4 v = make_float4(0.f, 0.f, 0.f, 0.f);
      if (m0 + row < N_NODES)
        v = *(const float4*)&A[(size_t)(m0 + row) * 512 + (kc & 511) + seg * 8];
      *(float4*)&As[row * 64 + sseg * 8] = v;
    }
    #pragma unroll
    for (int i = 0; i < 4; ++i){
      int f = tid + i * 256, row = f >> 3, seg = f & 7;
      int sseg = seg ^ (row & 7);
      *(float4*)&Bs[row * 64 + sseg * 8] =
        *(const float4*)&Bt[(size_t)(n0 + row) * 768 + kc + seg * 8];
    }
    __syncthreads();
    #pragma unroll
    for (int kk = 0; kk < 2; ++kk){
      const int seg = kk * 4 + (l >> 4);
      bfrag8 bfr[4];
      #pragma unroll
      for (int nr = 0; nr < 4; ++nr){
        const int br = wn + nr * 16 + lr;
        bfr[nr] = *(const bfrag8*)&Bs[br * 64 + (seg ^ (br & 7)) * 8];
      }
      #pragma unroll
      for (int mr = 0; mr < 4; ++mr){
        const int ar = wm + mr * 16 + lr;
        bfrag8 a = *(const bfrag8*)&As[ar * 64 + (seg ^ (ar & 7)) * 8];
        #pragma unroll
        for (int nr = 0; nr < 4; ++nr)
          acc[mr][nr] = __builtin_amdgcn_mfma_f32_16x16x32_bf16(a, bfr[nr], acc[mr][nr], 0, 0, 0);
      }
    }
    __syncthreads();
  }
  #pragma unroll
  for (int mr = 0; mr < 4; ++mr)
    #pragma unroll
    for (int nr = 0; nr < 4; ++nr){
      const int colg = n0 + wn + nr * 16 + lr;
      #pragma unroll
      for (int r = 0; r < 4; ++r){
        const int row = m0 + wm + mr * 16 + (l >> 4) * 4 + r;
        if (row < N_NODES)
          C[(size_t)row * 256 + colg] = __float2half(acc[mr][nr][r]);
      }
    }
}

// ------------- split-bf16 MFMA GEMM (standalone, for gemm2) -----------------
template<int BN, int OUT_HALF>
__global__ __launch_bounds__(256) void mfma_gemm(const unsigned short* __restrict__ A,
                                                 const unsigned short* __restrict__ Bt,
                                                 void* __restrict__ Cout,
                                                 int M, int ldc){
  __shared__ unsigned short As[128 * 64];
  __shared__ unsigned short Bs[BN * 64];
  const int tid = threadIdx.x;
  const int m0 = blockIdx.y * 128, n0 = blockIdx.x * BN;
  constexpr int NR = BN / 32;
  floatx4 acc[4][NR];
  #pragma unroll
  for (int mr = 0; mr < 4; ++mr)
    #pragma unroll
    for (int nr = 0; nr < NR; ++nr) acc[mr][nr] = (floatx4){0.f, 0.f, 0.f, 0.f};
  const int l = tid & 63, w = tid >> 6;
  const int wm = (w >> 1) * 64, wn = (w & 1) * (BN / 2);
  const int lr = l & 15;

  for (int kc = 0; kc < 768; kc += 64){
    #pragma unroll
    for (int i = 0; i < 4; ++i){
      int f = tid + i * 256, row = f >> 3, seg = f & 7;
      int sseg = seg ^ (row & 7);
      float4 v = make_float4(0.f, 0.f, 0.f, 0.f);
      if (m0 + row < M)
        v = *(const float4*)&A[(size_t)(m0 + row) * 512 + (kc & 511) + seg * 8];
      *(float4*)&As[row * 64 + sseg * 8] = v;
    }
    #pragma unroll
    for (int i = 0; i < BN / 32; ++i){
      int f = tid + i * 256, row = f >> 3, seg = f & 7;
      int sseg = seg ^ (row & 7);
      *(float4*)&Bs[row * 64 + sseg * 8] =
        *(const float4*)&Bt[(size_t)(n0 + row) * 768 + kc + seg * 8];
    }
    __syncthreads();
    #pragma unroll
    for (int kk = 0; kk < 2; ++kk){
      const int seg = kk * 4 + (l >> 4);
      bfrag8 bfr[NR];
      #pragma unroll
      for (int nr = 0; nr < NR; ++nr){
        const int br = wn + nr * 16 + lr;
        bfr[nr] = *(const bfrag8*)&Bs[br * 64 + (seg ^ (br & 7)) * 8];
      }
      #pragma unroll
      for (int mr = 0; mr < 4; ++mr){
        const int ar = wm + mr * 16 + lr;
        bfrag8 a = *(const bfrag8*)&As[ar * 64 + (seg ^ (ar & 7)) * 8];
        #pragma unroll
        for (int nr = 0; nr < NR; ++nr)
          acc[mr][nr] = __builtin_amdgcn_mfma_f32_16x16x32_bf16(a, bfr[nr], acc[mr][nr], 0, 0, 0);
      }
    }
    __syncthreads();
  }
  #pragma unroll
  for (int mr = 0; mr < 4; ++mr)
    #pragma unroll
    for (int nr = 0; nr < NR; ++nr){
      const int colg = n0 + wn + nr * 16 + lr;
      #pragma unroll
      for (int r = 0; r < 4; ++r){
        const int row = m0 + wm + mr * 16 + (l >> 4) * 4 + r;
        if (row < M){
          if (OUT_HALF)
            ((__half*)Cout)[(size_t)row * ldc + colg] = __float2half(acc[mr][nr][r]);
          else
            ((float*)Cout)[(size_t)row * ldc + colg] = acc[mr][nr][r];
        }
      }
    }
}

// ---- conv1 aggregate, WAVE-PER-NODE, online softmax, LDS-FREE --------------
__global__ __launch_bounds__(256) void k_agg1w(const __half* __restrict__ h1,
                                               const int* __restrict__ col,
                                               const int* __restrict__ row_start,
                                               const int* __restrict__ degv,
                                               const float* __restrict__ asrc,
                                               const float* __restrict__ adst,
                                               const float* __restrict__ b1,
                                               unsigned short* __restrict__ out1s){
  const int tid = threadIdx.x, wv = tid >> 6, lane = tid & 63;
  const int n = blockIdx.x * 4 + wv;
  const int base = row_start[n], dg = degv[n];
  const float4 ad4 = *(const float4*)&adst[(size_t)n * 4];
  const int hsel = lane >> 4;
  float m0 = -3e38f, m1 = -3e38f, m2 = -3e38f, m3 = -3e38f;
  float s = 0.f;
  float4 acc = make_float4(0.f, 0.f, 0.f, 0.f);

  for (int c0 = 0; c0 < dg; c0 += 64){
    const int cnt = min(64, dg - c0);
    float e0 = -3e38f, e1 = -3e38f, e2 = -3e38f, e3 = -3e38f;
    int src = 0;
    if (lane < cnt){
      src = col[base + c0 + lane];
      const float4 s4 = *(const float4*)&asrc[(size_t)src * 4];
      e0 = s4.x + ad4.x; e0 = e0 > 0.f ? e0 : 0.2f * e0;
      e1 = s4.y + ad4.y; e1 = e1 > 0.f ? e1 : 0.2f * e1;
      e2 = s4.z + ad4.z; e2 = e2 > 0.f ? e2 : 0.2f * e2;
      e3 = s4.w + ad4.w; e3 = e3 > 0.f ? e3 : 0.2f * e3;
    }
    const float M0 = wave_max(e0), M1 = wave_max(e1), M2 = wave_max(e2), M3 = wave_max(e3);
    const float nm0 = fmaxf(m0, M0), nm1 = fmaxf(m1, M1);
    const float nm2 = fmaxf(m2, M2), nm3 = fmaxf(m3, M3);
    const float mo = hsel == 0 ? m0 : hsel == 1 ? m1 : hsel == 2 ? m2 : m3;
    const float mn = hsel == 0 ? nm0 : hsel == 1 ? nm1 : hsel == 2 ? nm2 : nm3;
    const float r = __expf(mo - mn);   // 0 on first chunk
    s *= r; acc.x *= r; acc.y *= r; acc.z *= r; acc.w *= r;
    m0 = nm0; m1 = nm1; m2 = nm2; m3 = nm3;
    const float w0 = __expf(e0 - nm0), w1 = __expf(e1 - nm1);
    const float w2 = __expf(e2 - nm2), w3 = __expf(e3 - nm3);
    const float S0 = wave_sum(w0), S1 = wave_sum(w1);
    const float S2 = wave_sum(w2), S3 = wave_sum(w3);
    s += hsel == 0 ? S0 : hsel == 1 ? S1 : hsel == 2 ? S2 : S3;
    int j = 0;
    for (; j + 4 <= cnt; j += 4){
      float wt[4]; int sj[4];
      #pragma unroll
      for (int u = 0; u < 4; ++u){
        const float t0 = __shfl(w0, j + u), t1 = __shfl(w1, j + u);
        const float t2 = __shfl(w2, j + u), t3 = __shfl(w3, j + u);
        wt[u] = hsel == 0 ? t0 : hsel == 1 ? t1 : hsel == 2 ? t2 : t3;
        sj[u] = __shfl(src, j + u);
      }
      uint2 rw[4];
      #pragma unroll
      for (int u = 0; u < 4; ++u)
        rw[u] = *(const uint2*)&h1[(size_t)sj[u] * 256 + lane * 4];
      #pragma unroll
      for (int u = 0; u < 4; ++u){
        float2 f01 = __half22float2(*reinterpret_cast<const __half2*>(&rw[u].x));
        float2 f23 = __half22float2(*reinterpret_cast<const __half2*>(&rw[u].y));
        acc.x += wt[u] * f01.x; acc.y += wt[u] * f01.y;
        acc.z += wt[u] * f23.x; acc.w += wt[u] * f23.y;
      }
    }
    for (; j < cnt; ++j){
      const float t0 = __shfl(w0, j), t1 = __shfl(w1, j);
      const float t2 = __shfl(w2, j), t3 = __shfl(w3, j);
      const float wt = hsel == 0 ? t0 : hsel == 1 ? t1 : hsel == 2 ? t2 : t3;
      const int sj = __shfl(src, j);
      const uint2 rw = *(const uint2*)&h1[(size_t)sj * 256 + lane * 4];
      float2 f01 = __half22float2(*reinterpret_cast<const __half2*>(&rw.x));
      float2 f23 = __half22float2(*reinterpret_cast<const __half2*>(&rw.y));
      acc.x += wt * f01.x; acc.y += wt * f01.y;
      acc.z += wt * f23.x; acc.w += wt * f23.y;
    }
  }
  const float inv = 1.f / (s + 1e-16f);
  const float4 bb = *(const float4*)&b1[lane * 4];
  float o0 = acc.x * inv + bb.x; o0 = o0 > 0.f ? o0 : __expf(o0) - 1.f;
  float o1 = acc.y * inv + bb.y; o1 = o1 > 0.f ? o1 : __expf(o1) - 1.f;
  float o2 = acc.z * inv + bb.z; o2 = o2 > 0.f ? o2 : __expf(o2) - 1.f;
  float o3 = acc.w * inv + bb.w; o3 = o3 > 0.f ? o3 : __expf(o3) - 1.f;
  ushort4 hi4, lo4;
  hi4.x = f2bf(o0); lo4.x = f2bf(o0 - bf2f(hi4.x));
  hi4.y = f2bf(o1); lo4.y = f2bf(o1 - bf2f(hi4.y));
  hi4.z = f2bf(o2); lo4.z = f2bf(o2 - bf2f(hi4.z));
  hi4.w = f2bf(o3); lo4.w = f2bf(o3 - bf2f(hi4.w));
  *(ushort4*)&out1s[(size_t)n * 512 + lane * 4] = hi4;
  *(ushort4*)&out1s[(size_t)n * 512 + 256 + lane * 4] = lo4;
}

// ------------- conv2 attention scalars (4 nodes/block, fp16 t2) -------------
__global__ __launch_bounds__(256) void k_att2(const __half* __restrict__ t2,
                                              const float* __restrict__ a_src,
                                              const float* __restrict__ a_dst,
                                              float* __restrict__ asrc,
                                              float* __restrict__ adst){
  const int tid = threadIdx.x, wv = tid >> 6, lane = tid & 63;
  const int n = blockIdx.x * 4 + wv;
  float v = __half2float(t2[(size_t)n * 64 + lane]);
  float ps = wave_sum(v * a_src[lane]);
  float pd = wave_sum(v * a_dst[lane]);
  if (lane == 0){ asrc[n] = ps; adst[n] = pd; }
}

// ---- conv2 aggregate, WAVE-PER-NODE, LDS-FREE (2 edges/iter) ---------------
__global__ __launch_bounds__(256) void k_agg2w(const __half* __restrict__ t2,
                                               const int* __restrict__ col,
                                               const int* __restrict__ row_start,
                                               const int* __restrict__ degv,
                                               const float* __restrict__ asrc,
                                               const float* __restrict__ adst,
                                               const float* __restrict__ b2,
                                               const float* __restrict__ Wg,
                                               const float* __restrict__ bg,
                                               float* __restrict__ hf,
                                               float* __restrict__ attg){
  const int tid = threadIdx.x, wv = tid >> 6, lane = tid & 63;
  const int n = blockIdx.x * 4 + wv;
  const int base = row_start[n], dg = degv[n];
  const float ad = adst[n];
  const int half = lane >> 5, c2 = lane & 31;
  float m = -3e38f, s = 0.f;
  float2 acc = make_float2(0.f, 0.f);

  for (int c0 = 0; c0 < dg; c0 += 64){
    const int cnt = min(64, dg - c0);
    float e = -3e38f; int src = 0;
    if (lane < cnt){
      src = col[base + c0 + lane];
      e = asrc[src] + ad;
      e = e > 0.f ? e : 0.2f * e;
    }
    const float M = wave_max(e);
    const float mn = fmaxf(m, M);
    const float r = __expf(m - mn);
    s *= r; acc.x *= r; acc.y *= r;
    m = mn;
    const float w = __expf(e - mn);
    s += wave_sum(w);
    for (int j = 0; j < cnt; j += 2){
      const int j0 = j + half;
      if (j0 < cnt){
        const float wt = __shfl(w, j0);
        const int sj = __shfl(src, j0);
        const unsigned int rw = *(const unsigned int*)&t2[(size_t)sj * 64 + c2 * 2];
        float2 f = __half22float2(*reinterpret_cast<const __half2*>(&rw));
        acc.x += wt * f.x; acc.y += wt * f.y;
      }
    }
  }
  acc.x += __shfl_xor(acc.x, 32);
  acc.y += __shfl_xor(acc.y, 32);
  const float inv = 1.f / (s + 1e-16f);
  float p = 0.f;
  if (half == 0){
    float o0 = acc.x * inv + b2[c2 * 2];     o0 = o0 > 0.f ? o0 : __expf(o0) - 1.f;
    float o1 = acc.y * inv + b2[c2 * 2 + 1]; o1 = o1 > 0.f ? o1 : __expf(o1) - 1.f;
    *(float2*)&hf[(size_t)n * 64 + c2 * 2] = make_float2(o0, o1);
    p = o0 * Wg[c2 * 2] + o1 * Wg[c2 * 2 + 1];
  }
  p = wave_sum(p);
  if (lane == 0) attg[n] = p + bg[0];
}

// ----- per-graph softmax pooling + classifier, 4 waves per graph ------------
__global__ __launch_bounds__(256) void k_pool(const float* __restrict__ hf,
                                              const float* __restrict__ attg,
                                              const int* __restrict__ batch,
                                              const float* __restrict__ Wc1,
                                              const float* __restrict__ bc1,
                                              const float* __restrict__ Wc2,
                                              const float* __restrict__ bc2,
                                              float* __restrict__ out){
  __shared__ float redm[4], reds[4];
  __shared__ float pacc[4][64];
  __shared__ float pooled[64];
  __shared__ float hid[32];
  const int g = blockIdx.x, tid = threadIdx.x;
  const int wv = tid >> 6, lane = tid & 63;
  int lo = 0, hi = N_NODES;
  while (lo < hi){ int mid = (lo + hi) >> 1; if (batch[mid] < g) lo = mid + 1; else hi = mid; }
  const int s0 = lo;
  hi = N_NODES;
  while (lo < hi){ int mid = (lo + hi) >> 1; if (batch[mid] < g + 1) lo = mid + 1; else hi = mid; }
  const int s1 = lo;
  float lm = -3e38f;
  for (int j = s0 + tid; j < s1; j += 256) lm = fmaxf(lm, attg[j]);
  lm = wave_max(lm);
  if (lane == 0) redm[wv] = lm;
  __syncthreads();
  lm = fmaxf(fmaxf(redm[0], redm[1]), fmaxf(redm[2], redm[3]));
  float ls = 0.f;
  for (int j = s0 + tid; j < s1; j += 256) ls += __expf(attg[j] - lm);
  ls = wave_sum(ls);
  if (lane == 0) reds[wv] = ls;
  __syncthreads();
  ls = reds[0] + reds[1] + reds[2] + reds[3];
  const float inv = 1.f / (ls + 1e-16f);
  float acc = 0.f;
  for (int j = s0 + wv; j < s1; j += 4)
    acc += __expf(attg[j] - lm) * hf[(size_t)j * 64 + lane];
  pacc[wv][lane] = acc;
  __syncthreads();
  if (tid < 64)
    pooled[tid] = (pacc[0][tid] + pacc[1][tid] + pacc[2][tid] + pacc[3][tid]) * inv;
  __syncthreads();
  if (tid < 32){
    float t = bc1[tid];
    #pragma unroll
    for (int c = 0; c < 64; ++c) t += pooled[c] * Wc1[c * 32 + tid];
    hid[tid] = t > 0.f ? t : 0.f;
  }
  __syncthreads();
  if (tid < 2){
    float t = bc2[tid];
    #pragma unroll
    for (int c = 0; c < 32; ++c) t += hid[c] * Wc2[c * 2 + tid];
    out[g * 2 + tid] = t;
  }
}

extern "C" void kernel_launch(void* const* d_in, const int* in_sizes, int n_in,
                              void* d_out, int out_size, void* d_ws, size_t ws_size,
                              hipStream_t stream){
  const float* x    = (const float*)d_in[0];
  const int*   ei   = (const int*)d_in[1];
  const int*   batch= (const int*)d_in[2];
  const float* W1   = (const float*)d_in[3];
  const float* as1  = (const float*)d_in[4];
  const float* ad1  = (const float*)d_in[5];
  const float* b1   = (const float*)d_in[6];
  const float* W2   = (const float*)d_in[7];
  const float* as2  = (const float*)d_in[8];
  const float* ad2  = (const float*)d_in[9];
  const float* b2   = (const float*)d_in[10];
  const float* Wg   = (const float*)d_in[11];
  const float* bg   = (const float*)d_in[12];
  const float* Wc1  = (const float*)d_in[13];
  const float* bc1  = (const float*)d_in[14];
  const float* Wc2  = (const float*)d_in[15];
  const float* bc2  = (const float*)d_in[16];

  char* ws = (char*)d_ws;
  unsigned short* x2s   = (unsigned short*)(ws + 0LL);         // [N][512] bf16 split
  unsigned short* out1s = (unsigned short*)(ws + 0LL);         // same region (x2 dead after gemm1)
  __half* h1h   = (__half*)(ws + 51200000LL);   // [N][256] fp16 = 25.6MB
  __half* t2h   = (__half*)(ws + 102400000LL);  // [N][64] fp16 = 6.4MB
  float* hf     = (float*)(ws + 115200000LL);   // 12.8MB (written late by k_agg2w)
  float* P      = (float*)(ws + 115200000LL);   // 8KB (dead before hf written)
  unsigned short* W1B3t = (unsigned short*)(ws + 115208192LL); // 393216B
  unsigned short* W2B3t = (unsigned short*)(ws + 115601408LL); // 98304B
  float* asrc1  = (float*)(ws + 128000000LL);   // 800KB
  float* adst1  = (float*)(ws + 128800000LL);   // 800KB
  float* asrc2  = (float*)(ws + 129600000LL);   // 200KB
  float* adst2  = (float*)(ws + 129800000LL);   // 200KB
  float* attg   = (float*)(ws + 130000000LL);   // 200KB
  int*   deg    = (int*)  (ws + 130200000LL);   // 200KB
  int*   fill   = (int*)  (ws + 130400000LL);   // 200KB
  int*   row_st = (int*)  (ws + 130600256LL);   // 200KB
  int*   col    = (int*)  (ws + 130800256LL);   // 3.4MB
  float* outf   = (float*)d_out;

  hipMemsetAsync(ws + 130200000LL, 0, 400256, stream);

  // K1: count + W-splits + P projection (all independent)
  k_prepc<<<NB_COUNT + 322, 256, 0, stream>>>(ei, W1, W2, as1, ad1, deg, W1B3t, W2B3t, P);
  // K2: att1 scalars + x split (needs P) + CSR scan (needs deg)
  k_att1s<<<12501, 256, 0, stream>>>(x, P, asrc1, adst1, x2s, deg, row_st);
  // K3: gemm1 (needs x2s, W1B3t) + CSR fill (needs row_st)
  k_fg1<<<782 + NB_COUNT, 256, 0, stream>>>(x2s, W1B3t, h1h, ei, row_st, fill, col);
  // K4
  k_agg1w<<<N_NODES / 4, 256, 0, stream>>>(h1h, col, row_st, deg, asrc1, adst1, b1, out1s);
  // K5
  mfma_gemm<64, 1><<<dim3(1, 391), 256, 0, stream>>>(out1s, W2B3t, (void*)t2h, N_NODES, 64);
  // K6
  k_att2<<<N_NODES / 4, 256, 0, stream>>>(t2h, as2, ad2, asrc2, adst2);
  // K7
  k_agg2w<<<N_NODES / 4, 256, 0, stream>>>(t2h, col, row_st, deg, asrc2, adst2, b2, Wg, bg, hf, attg);
  // K8
  k_pool<<<NGRAPH, 256, 0, stream>>>(hf, attg, batch, Wc1, bc1, Wc2, bc2, outf);
}

// Round 12
// 476.714 us; speedup vs baseline: 1.1245x; 1.1245x over previous
//
#include <hip/hip_runtime.h>
#include <hip/hip_bf16.h>
#include <hip/hip_fp16.h>
#include <math.h>

#define N_NODES 50000
#define N_EDGES 800000
#define M_EDGES (N_EDGES + N_NODES)
#define NGRAPH 512

typedef __attribute__((ext_vector_type(8))) short bfrag8;
typedef __attribute__((ext_vector_type(4))) float floatx4;

__device__ __forceinline__ float wave_max(float v){
  #pragma unroll
  for (int o = 32; o; o >>= 1) v = fmaxf(v, __shfl_xor(v, o));
  return v;
}
__device__ __forceinline__ float wave_sum(float v){
  #pragma unroll
  for (int o = 32; o; o >>= 1) v += __shfl_xor(v, o);
  return v;
}
__device__ __forceinline__ unsigned short f2bf(float f){
  union { float f; unsigned int u; } v; v.f = f;
  unsigned int r = v.u + 0x7FFFu + ((v.u >> 16) & 1u);
  return (unsigned short)(r >> 16);
}
__device__ __forceinline__ float bf2f(unsigned short h){
  union { unsigned int u; float f; } v; v.u = ((unsigned int)h) << 16; return v.f;
}

// ---- fused prep: edge-count + W1/W2 split panels + P projection ------------
// blocks [0,3321): count; [3321,3577): W1 col; [3577,3641): W2 col; [3641]: projP
#define NB_COUNT 3321
__global__ __launch_bounds__(256) void k_prepc(const int* __restrict__ ei,
                                               const float* __restrict__ W1,
                                               const float* __restrict__ W2,
                                               const float* __restrict__ as1,
                                               const float* __restrict__ ad1,
                                               int* __restrict__ deg,
                                               unsigned short* __restrict__ W1B3t,
                                               unsigned short* __restrict__ W2B3t,
                                               float* __restrict__ P){
  const int b = blockIdx.x, tid = threadIdx.x;
  if (b < NB_COUNT){
    int e = b * 256 + tid;
    if (e < M_EDGES){
      int dst = (e < N_EDGES) ? ei[N_EDGES + e] : (e - N_EDGES);
      atomicAdd(&deg[dst], 1);
    }
  } else if (b < NB_COUNT + 256){
    const int n = b - NB_COUNT;
    #pragma unroll
    for (int p = 0; p < 3; ++p){
      const int k = p * 256 + tid;
      float w = W1[(size_t)(k & 255) * 256 + n];
      unsigned short hi = f2bf(w);
      W1B3t[(size_t)n * 768 + k] = (k < 512) ? hi : f2bf(w - bf2f(hi));
    }
  } else if (b < NB_COUNT + 320){
    const int n = b - (NB_COUNT + 256);
    #pragma unroll
    for (int p = 0; p < 3; ++p){
      const int k = p * 256 + tid;
      float w = W2[(size_t)(k & 255) * 64 + n];
      unsigned short hi = f2bf(w);
      W2B3t[(size_t)n * 768 + k] = (k < 512) ? hi : f2bf(w - bf2f(hi));
    }
  } else {
    const int k = tid;
    float acc[8] = {0.f,0.f,0.f,0.f,0.f,0.f,0.f,0.f};
    for (int c = 0; c < 64; ++c){
      #pragma unroll
      for (int h = 0; h < 4; ++h){
        float w = W1[k * 256 + h * 64 + c];
        acc[h]     += w * as1[h * 64 + c];
        acc[4 + h] += w * ad1[h * 64 + c];
      }
    }
    #pragma unroll
    for (int j = 0; j < 8; ++j) P[k * 8 + j] = acc[j];
  }
}

// --- fused: CSR scan (block 0, starts first) + att1 scalars + x split -------
__global__ __launch_bounds__(256) void k_att1s(const float* __restrict__ x,
                                               const float* __restrict__ P,
                                               float* __restrict__ asrc,
                                               float* __restrict__ adst,
                                               unsigned short* __restrict__ x2,
                                               const int* __restrict__ deg,
                                               int* __restrict__ row_start){
  __shared__ int wsum[4];
  const int tid = threadIdx.x;
  const int wv = tid >> 6, lane = tid & 63;
  if (blockIdx.x == 0){
    // two-phase exclusive prefix scan, int4-vectorized (CH=208 -> 832B aligned)
    const int CH = 208;                 // 208*256 = 53248 >= N_NODES
    const int beg = tid * CH;
    const int end = min(beg + CH, N_NODES);
    int tot = 0;
    int i = beg;
    for (; i + 4 <= end; i += 4){
      const int4 v = *(const int4*)&deg[i];
      tot += v.x + v.y + v.z + v.w;
    }
    for (; i < end; ++i) tot += deg[i];
    int xs = tot;
    #pragma unroll
    for (int o = 1; o < 64; o <<= 1){
      int t = __shfl_up(xs, o);
      if (lane >= o) xs += t;
    }
    if (lane == 63) wsum[wv] = xs;
    __syncthreads();
    int off = 0;
    for (int k = 0; k < wv; ++k) off += wsum[k];
    int run = off + xs - tot;
    i = beg;
    for (; i + 4 <= end; i += 4){
      const int4 v = *(const int4*)&deg[i];
      int4 w;
      w.x = run; run += v.x;
      w.y = run; run += v.y;
      w.z = run; run += v.z;
      w.w = run; run += v.w;
      *(int4*)&row_start[i] = w;
    }
    for (; i < end; ++i){ row_start[i] = run; run += deg[i]; }
  } else {
    const int n = (blockIdx.x - 1) * 4 + wv;
    const int lane4 = lane * 4;
    // per-lane P rows in registers (P is 8KB, L1/L2-resident; no LDS)
    float4 Pa[4], Pb[4];
    #pragma unroll
    for (int c = 0; c < 4; ++c){
      Pa[c] = *(const float4*)&P[(lane4 + c) * 8];
      Pb[c] = *(const float4*)&P[(lane4 + c) * 8 + 4];
    }
    float4 xv = *(const float4*)&x[(size_t)n * 256 + lane4];
    ushort4 hi4, lo4;
    hi4.x = f2bf(xv.x); lo4.x = f2bf(xv.x - bf2f(hi4.x));
    hi4.y = f2bf(xv.y); lo4.y = f2bf(xv.y - bf2f(hi4.y));
    hi4.z = f2bf(xv.z); lo4.z = f2bf(xv.z - bf2f(hi4.z));
    hi4.w = f2bf(xv.w); lo4.w = f2bf(xv.w - bf2f(hi4.w));
    *(ushort4*)&x2[(size_t)n * 512 + lane4] = hi4;
    *(ushort4*)&x2[(size_t)n * 512 + 256 + lane4] = lo4;
    float p[8];
    p[0] = xv.x*Pa[0].x + xv.y*Pa[1].x + xv.z*Pa[2].x + xv.w*Pa[3].x;
    p[1] = xv.x*Pa[0].y + xv.y*Pa[1].y + xv.z*Pa[2].y + xv.w*Pa[3].y;
    p[2] = xv.x*Pa[0].z + xv.y*Pa[1].z + xv.z*Pa[2].z + xv.w*Pa[3].z;
    p[3] = xv.x*Pa[0].w + xv.y*Pa[1].w + xv.z*Pa[2].w + xv.w*Pa[3].w;
    p[4] = xv.x*Pb[0].x + xv.y*Pb[1].x + xv.z*Pb[2].x + xv.w*Pb[3].x;
    p[5] = xv.x*Pb[0].y + xv.y*Pb[1].y + xv.z*Pb[2].y + xv.w*Pb[3].y;
    p[6] = xv.x*Pb[0].z + xv.y*Pb[1].z + xv.z*Pb[2].z + xv.w*Pb[3].z;
    p[7] = xv.x*Pb[0].w + xv.y*Pb[1].w + xv.z*Pb[2].w + xv.w*Pb[3].w;
    #pragma unroll
    for (int j = 0; j < 8; ++j) p[j] = wave_sum(p[j]);
    if (lane == 0){
      *(float4*)&asrc[n * 4] = make_float4(p[0], p[1], p[2], p[3]);
      *(float4*)&adst[n * 4] = make_float4(p[4], p[5], p[6], p[7]);
    }
  }
}

// ---- fused: split-bf16 MFMA GEMM1 (BM=128,BN=128) + CSR fill ---------------
// blocks [0,782): gemm (bx = b&1, by = b>>1); [782, 782+3321): fill
__global__ __launch_bounds__(256) void k_fg1(const unsigned short* __restrict__ A,
                                             const unsigned short* __restrict__ Bt,
                                             __half* __restrict__ C,
                                             const int* __restrict__ ei,
                                             const int* __restrict__ row_start,
                                             int* __restrict__ fill,
                                             int* __restrict__ col){
  __shared__ unsigned short As[128 * 64];
  __shared__ unsigned short Bs[128 * 64];
  const int tid = threadIdx.x;
  if (blockIdx.x >= 782){
    int e = (blockIdx.x - 782) * 256 + tid;
    if (e < M_EDGES){
      int src, dst;
      if (e < N_EDGES){ src = ei[e]; dst = ei[N_EDGES + e]; }
      else { src = dst = e - N_EDGES; }
      int slot = row_start[dst] + atomicAdd(&fill[dst], 1);
      col[slot] = src;
    }
    return;
  }
  const int m0 = (blockIdx.x >> 1) * 128, n0 = (blockIdx.x & 1) * 128;
  floatx4 acc[4][4];
  #pragma unroll
  for (int mr = 0; mr < 4; ++mr)
    #pragma unroll
    for (int nr = 0; nr < 4; ++nr) acc[mr][nr] = (floatx4){0.f, 0.f, 0.f, 0.f};
  const int l = tid & 63, w = tid >> 6;
  const int wm = (w >> 1) * 64, wn = (w & 1) * 64;
  const int lr = l & 15;

  for (int kc = 0; kc < 768; kc += 64){
    #pragma unroll
    for (int i = 0; i < 4; ++i){
      int f = tid + i * 256, row = f >> 3, seg = f & 7;
      int sseg = seg ^ (row & 7);
      float4 v = make_float4(0.f, 0.f, 0.f, 0.f);
      if (m0 + row < N_NODES)
        v = *(const float4*)&A[(size_t)(m0 + row) * 512 + (kc & 511) + seg * 8];
      *(float4*)&As[row * 64 + sseg * 8] = v;
    }
    #pragma unroll
    for (int i = 0; i < 4; ++i){
      int f = tid + i * 256, row = f >> 3, seg = f & 7;
      int sseg = seg ^ (row & 7);
      *(float4*)&Bs[row * 64 + sseg * 8] =
        *(const float4*)&Bt[(size_t)(n0 + row) * 768 + kc + seg * 8];
    }
    __syncthreads();
    #pragma unroll
    for (int kk = 0; kk < 2; ++kk){
      const int seg = kk * 4 + (l >> 4);
      bfrag8 bfr[4];
      #pragma unroll
      for (int nr = 0; nr < 4; ++nr){
        const int br = wn + nr * 16 + lr;
        bfr[nr] = *(const bfrag8*)&Bs[br * 64 + (seg ^ (br & 7)) * 8];
      }
      #pragma unroll
      for (int mr = 0; mr < 4; ++mr){
        const int ar = wm + mr * 16 + lr;
        bfrag8 a = *(const bfrag8*)&As[ar * 64 + (seg ^ (ar & 7)) * 8];
        #pragma unroll
        for (int nr = 0; nr < 4; ++nr)
          acc[mr][nr] = __builtin_amdgcn_mfma_f32_16x16x32_bf16(a, bfr[nr], acc[mr][nr], 0, 0, 0);
      }
    }
    __syncthreads();
  }
  #pragma unroll
  for (int mr = 0; mr < 4; ++mr)
    #pragma unroll
    for (int nr = 0; nr < 4; ++nr){
      const int colg = n0 + wn + nr * 16 + lr;
      #pragma unroll
      for (int r = 0; r < 4; ++r){
        const int row = m0 + wm + mr * 16 + (l >> 4) * 4 + r;
        if (row < N_NODES)
          C[(size_t)row * 256 + colg] = __float2half(acc[mr][nr][r]);
      }
    }
}

// ------------- split-bf16 MFMA GEMM (standalone, for gemm2) -----------------
template<int BN, int OUT_HALF>
__global__ __launch_bounds__(256) void mfma_gemm(const unsigned short* __restrict__ A,
                                                 const unsigned short* __restrict__ Bt,
                                                 void* __restrict__ Cout,
                                                 int M, int ldc){
  __shared__ unsigned short As[128 * 64];
  __shared__ unsigned short Bs[BN * 64];
  const int tid = threadIdx.x;
  const int m0 = blockIdx.y * 128, n0 = blockIdx.x * BN;
  constexpr int NR = BN / 32;
  floatx4 acc[4][NR];
  #pragma unroll
  for (int mr = 0; mr < 4; ++mr)
    #pragma unroll
    for (int nr = 0; nr < NR; ++nr) acc[mr][nr] = (floatx4){0.f, 0.f, 0.f, 0.f};
  const int l = tid & 63, w = tid >> 6;
  const int wm = (w >> 1) * 64, wn = (w & 1) * (BN / 2);
  const int lr = l & 15;

  for (int kc = 0; kc < 768; kc += 64){
    #pragma unroll
    for (int i = 0; i < 4; ++i){
      int f = tid + i * 256, row = f >> 3, seg = f & 7;
      int sseg = seg ^ (row & 7);
      float4 v = make_float4(0.f, 0.f, 0.f, 0.f);
      if (m0 + row < M)
        v = *(const float4*)&A[(size_t)(m0 + row) * 512 + (kc & 511) + seg * 8];
      *(float4*)&As[row * 64 + sseg * 8] = v;
    }
    #pragma unroll
    for (int i = 0; i < BN / 32; ++i){
      int f = tid + i * 256, row = f >> 3, seg = f & 7;
      int sseg = seg ^ (row & 7);
      *(float4*)&Bs[row * 64 + sseg * 8] =
        *(const float4*)&Bt[(size_t)(n0 + row) * 768 + kc + seg * 8];
    }
    __syncthreads();
    #pragma unroll
    for (int kk = 0; kk < 2; ++kk){
      const int seg = kk * 4 + (l >> 4);
      bfrag8 bfr[NR];
      #pragma unroll
      for (int nr = 0; nr < NR; ++nr){
        const int br = wn + nr * 16 + lr;
        bfr[nr] = *(const bfrag8*)&Bs[br * 64 + (seg ^ (br & 7)) * 8];
      }
      #pragma unroll
      for (int mr = 0; mr < 4; ++mr){
        const int ar = wm + mr * 16 + lr;
        bfrag8 a = *(const bfrag8*)&As[ar * 64 + (seg ^ (ar & 7)) * 8];
        #pragma unroll
        for (int nr = 0; nr < NR; ++nr)
          acc[mr][nr] = __builtin_amdgcn_mfma_f32_16x16x32_bf16(a, bfr[nr], acc[mr][nr], 0, 0, 0);
      }
    }
    __syncthreads();
  }
  #pragma unroll
  for (int mr = 0; mr < 4; ++mr)
    #pragma unroll
    for (int nr = 0; nr < NR; ++nr){
      const int colg = n0 + wn + nr * 16 + lr;
      #pragma unroll
      for (int r = 0; r < 4; ++r){
        const int row = m0 + wm + mr * 16 + (l >> 4) * 4 + r;
        if (row < M){
          if (OUT_HALF)
            ((__half*)Cout)[(size_t)row * ldc + colg] = __float2half(acc[mr][nr][r]);
          else
            ((float*)Cout)[(size_t)row * ldc + colg] = acc[mr][nr][r];
        }
      }
    }
}

// ---- conv1 aggregate, WAVE-PER-NODE, online softmax, LDS-FREE --------------
__global__ __launch_bounds__(256) void k_agg1w(const __half* __restrict__ h1,
                                               const int* __restrict__ col,
                                               const int* __restrict__ row_start,
                                               const int* __restrict__ degv,
                                               const float* __restrict__ asrc,
                                               const float* __restrict__ adst,
                                               const float* __restrict__ b1,
                                               unsigned short* __restrict__ out1s){
  const int tid = threadIdx.x, wv = tid >> 6, lane = tid & 63;
  const int n = blockIdx.x * 4 + wv;
  const int base = row_start[n], dg = degv[n];
  const float4 ad4 = *(const float4*)&adst[(size_t)n * 4];
  const int hsel = lane >> 4;
  float m0 = -3e38f, m1 = -3e38f, m2 = -3e38f, m3 = -3e38f;
  float s = 0.f;
  float4 acc = make_float4(0.f, 0.f, 0.f, 0.f);

  for (int c0 = 0; c0 < dg; c0 += 64){
    const int cnt = min(64, dg - c0);
    float e0 = -3e38f, e1 = -3e38f, e2 = -3e38f, e3 = -3e38f;
    int src = 0;
    if (lane < cnt){
      src = col[base + c0 + lane];
      const float4 s4 = *(const float4*)&asrc[(size_t)src * 4];
      e0 = s4.x + ad4.x; e0 = e0 > 0.f ? e0 : 0.2f * e0;
      e1 = s4.y + ad4.y; e1 = e1 > 0.f ? e1 : 0.2f * e1;
      e2 = s4.z + ad4.z; e2 = e2 > 0.f ? e2 : 0.2f * e2;
      e3 = s4.w + ad4.w; e3 = e3 > 0.f ? e3 : 0.2f * e3;
    }
    const float M0 = wave_max(e0), M1 = wave_max(e1), M2 = wave_max(e2), M3 = wave_max(e3);
    const float nm0 = fmaxf(m0, M0), nm1 = fmaxf(m1, M1);
    const float nm2 = fmaxf(m2, M2), nm3 = fmaxf(m3, M3);
    const float mo = hsel == 0 ? m0 : hsel == 1 ? m1 : hsel == 2 ? m2 : m3;
    const float mn = hsel == 0 ? nm0 : hsel == 1 ? nm1 : hsel == 2 ? nm2 : nm3;
    const float r = __expf(mo - mn);   // 0 on first chunk
    s *= r; acc.x *= r; acc.y *= r; acc.z *= r; acc.w *= r;
    m0 = nm0; m1 = nm1; m2 = nm2; m3 = nm3;
    const float w0 = __expf(e0 - nm0), w1 = __expf(e1 - nm1);
    const float w2 = __expf(e2 - nm2), w3 = __expf(e3 - nm3);
    const float S0 = wave_sum(w0), S1 = wave_sum(w1);
    const float S2 = wave_sum(w2), S3 = wave_sum(w3);
    s += hsel == 0 ? S0 : hsel == 1 ? S1 : hsel == 2 ? S2 : S3;
    int j = 0;
    for (; j + 4 <= cnt; j += 4){
      float wt[4]; int sj[4];
      #pragma unroll
      for (int u = 0; u < 4; ++u){
        const float t0 = __shfl(w0, j + u), t1 = __shfl(w1, j + u);
        const float t2 = __shfl(w2, j + u), t3 = __shfl(w3, j + u);
        wt[u] = hsel == 0 ? t0 : hsel == 1 ? t1 : hsel == 2 ? t2 : t3;
        sj[u] = __shfl(src, j + u);
      }
      uint2 rw[4];
      #pragma unroll
      for (int u = 0; u < 4; ++u)
        rw[u] = *(const uint2*)&h1[(size_t)sj[u] * 256 + lane * 4];
      #pragma unroll
      for (int u = 0; u < 4; ++u){
        float2 f01 = __half22float2(*reinterpret_cast<const __half2*>(&rw[u].x));
        float2 f23 = __half22float2(*reinterpret_cast<const __half2*>(&rw[u].y));
        acc.x += wt[u] * f01.x; acc.y += wt[u] * f01.y;
        acc.z += wt[u] * f23.x; acc.w += wt[u] * f23.y;
      }
    }
    for (; j < cnt; ++j){
      const float t0 = __shfl(w0, j), t1 = __shfl(w1, j);
      const float t2 = __shfl(w2, j), t3 = __shfl(w3, j);
      const float wt = hsel == 0 ? t0 : hsel == 1 ? t1 : hsel == 2 ? t2 : t3;
      const int sj = __shfl(src, j);
      const uint2 rw = *(const uint2*)&h1[(size_t)sj * 256 + lane * 4];
      float2 f01 = __half22float2(*reinterpret_cast<const __half2*>(&rw.x));
      float2 f23 = __half22float2(*reinterpret_cast<const __half2*>(&rw.y));
      acc.x += wt * f01.x; acc.y += wt * f01.y;
      acc.z += wt * f23.x; acc.w += wt * f23.y;
    }
  }
  const float inv = 1.f / (s + 1e-16f);
  const float4 bb = *(const float4*)&b1[lane * 4];
  float o0 = acc.x * inv + bb.x; o0 = o0 > 0.f ? o0 : __expf(o0) - 1.f;
  float o1 = acc.y * inv + bb.y; o1 = o1 > 0.f ? o1 : __expf(o1) - 1.f;
  float o2 = acc.z * inv + bb.z; o2 = o2 > 0.f ? o2 : __expf(o2) - 1.f;
  float o3 = acc.w * inv + bb.w; o3 = o3 > 0.f ? o3 : __expf(o3) - 1.f;
  ushort4 hi4, lo4;
  hi4.x = f2bf(o0); lo4.x = f2bf(o0 - bf2f(hi4.x));
  hi4.y = f2bf(o1); lo4.y = f2bf(o1 - bf2f(hi4.y));
  hi4.z = f2bf(o2); lo4.z = f2bf(o2 - bf2f(hi4.z));
  hi4.w = f2bf(o3); lo4.w = f2bf(o3 - bf2f(hi4.w));
  *(ushort4*)&out1s[(size_t)n * 512 + lane * 4] = hi4;
  *(ushort4*)&out1s[(size_t)n * 512 + 256 + lane * 4] = lo4;
}

// ------------- conv2 attention scalars (4 nodes/block, fp16 t2) -------------
__global__ __launch_bounds__(256) void k_att2(const __half* __restrict__ t2,
                                              const float* __restrict__ a_src,
                                              const float* __restrict__ a_dst,
                                              float* __restrict__ asrc,
                                              float* __restrict__ adst){
  const int tid = threadIdx.x, wv = tid >> 6, lane = tid & 63;
  const int n = blockIdx.x * 4 + wv;
  float v = __half2float(t2[(size_t)n * 64 + lane]);
  float ps = wave_sum(v * a_src[lane]);
  float pd = wave_sum(v * a_dst[lane]);
  if (lane == 0){ asrc[n] = ps; adst[n] = pd; }
}

// ---- conv2 aggregate, WAVE-PER-NODE, LDS-FREE (2 edges/iter) ---------------
__global__ __launch_bounds__(256) void k_agg2w(const __half* __restrict__ t2,
                                               const int* __restrict__ col,
                                               const int* __restrict__ row_start,
                                               const int* __restrict__ degv,
                                               const float* __restrict__ asrc,
                                               const float* __restrict__ adst,
                                               const float* __restrict__ b2,
                                               const float* __restrict__ Wg,
                                               const float* __restrict__ bg,
                                               float* __restrict__ hf,
                                               float* __restrict__ attg){
  const int tid = threadIdx.x, wv = tid >> 6, lane = tid & 63;
  const int n = blockIdx.x * 4 + wv;
  const int base = row_start[n], dg = degv[n];
  const float ad = adst[n];
  const int half = lane >> 5, c2 = lane & 31;
  float m = -3e38f, s = 0.f;
  float2 acc = make_float2(0.f, 0.f);

  for (int c0 = 0; c0 < dg; c0 += 64){
    const int cnt = min(64, dg - c0);
    float e = -3e38f; int src = 0;
    if (lane < cnt){
      src = col[base + c0 + lane];
      e = asrc[src] + ad;
      e = e > 0.f ? e : 0.2f * e;
    }
    const float M = wave_max(e);
    const float mn = fmaxf(m, M);
    const float r = __expf(m - mn);
    s *= r; acc.x *= r; acc.y *= r;
    m = mn;
    const float w = __expf(e - mn);
    s += wave_sum(w);
    for (int j = 0; j < cnt; j += 2){
      const int j0 = j + half;
      if (j0 < cnt){
        const float wt = __shfl(w, j0);
        const int sj = __shfl(src, j0);
        const unsigned int rw = *(const unsigned int*)&t2[(size_t)sj * 64 + c2 * 2];
        float2 f = __half22float2(*reinterpret_cast<const __half2*>(&rw));
        acc.x += wt * f.x; acc.y += wt * f.y;
      }
    }
  }
  acc.x += __shfl_xor(acc.x, 32);
  acc.y += __shfl_xor(acc.y, 32);
  const float inv = 1.f / (s + 1e-16f);
  float p = 0.f;
  if (half == 0){
    float o0 = acc.x * inv + b2[c2 * 2];     o0 = o0 > 0.f ? o0 : __expf(o0) - 1.f;
    float o1 = acc.y * inv + b2[c2 * 2 + 1]; o1 = o1 > 0.f ? o1 : __expf(o1) - 1.f;
    *(float2*)&hf[(size_t)n * 64 + c2 * 2] = make_float2(o0, o1);
    p = o0 * Wg[c2 * 2] + o1 * Wg[c2 * 2 + 1];
  }
  p = wave_sum(p);
  if (lane == 0) attg[n] = p + bg[0];
}

// ----- per-graph softmax pooling + classifier, 4 waves per graph ------------
__global__ __launch_bounds__(256) void k_pool(const float* __restrict__ hf,
                                              const float* __restrict__ attg,
                                              const int* __restrict__ batch,
                                              const float* __restrict__ Wc1,
                                              const float* __restrict__ bc1,
                                              const float* __restrict__ Wc2,
                                              const float* __restrict__ bc2,
                                              float* __restrict__ out){
  __shared__ float redm[4], reds[4];
  __shared__ float pacc[4][64];
  __shared__ float pooled[64];
  __shared__ float hid[32];
  const int g = blockIdx.x, tid = threadIdx.x;
  const int wv = tid >> 6, lane = tid & 63;
  int lo = 0, hi = N_NODES;
  while (lo < hi){ int mid = (lo + hi) >> 1; if (batch[mid] < g) lo = mid + 1; else hi = mid; }
  const int s0 = lo;
  hi = N_NODES;
  while (lo < hi){ int mid = (lo + hi) >> 1; if (batch[mid] < g + 1) lo = mid + 1; else hi = mid; }
  const int s1 = lo;
  float lm = -3e38f;
  for (int j = s0 + tid; j < s1; j += 256) lm = fmaxf(lm, attg[j]);
  lm = wave_max(lm);
  if (lane == 0) redm[wv] = lm;
  __syncthreads();
  lm = fmaxf(fmaxf(redm[0], redm[1]), fmaxf(redm[2], redm[3]));
  float ls = 0.f;
  for (int j = s0 + tid; j < s1; j += 256) ls += __expf(attg[j] - lm);
  ls = wave_sum(ls);
  if (lane == 0) reds[wv] = ls;
  __syncthreads();
  ls = reds[0] + reds[1] + reds[2] + reds[3];
  const float inv = 1.f / (ls + 1e-16f);
  float acc = 0.f;
  for (int j = s0 + wv; j < s1; j += 4)
    acc += __expf(attg[j] - lm) * hf[(size_t)j * 64 + lane];
  pacc[wv][lane] = acc;
  __syncthreads();
  if (tid < 64)
    pooled[tid] = (pacc[0][tid] + pacc[1][tid] + pacc[2][tid] + pacc[3][tid]) * inv;
  __syncthreads();
  if (tid < 32){
    float t = bc1[tid];
    #pragma unroll
    for (int c = 0; c < 64; ++c) t += pooled[c] * Wc1[c * 32 + tid];
    hid[tid] = t > 0.f ? t : 0.f;
  }
  __syncthreads();
  if (tid < 2){
    float t = bc2[tid];
    #pragma unroll
    for (int c = 0; c < 32; ++c) t += hid[c] * Wc2[c * 2 + tid];
    out[g * 2 + tid] = t;
  }
}

extern "C" void kernel_launch(void* const* d_in, const int* in_sizes, int n_in,
                              void* d_out, int out_size, void* d_ws, size_t ws_size,
                              hipStream_t stream){
  const float* x    = (const float*)d_in[0];
  const int*   ei   = (const int*)d_in[1];
  const int*   batch= (const int*)d_in[2];
  const float* W1   = (const float*)d_in[3];
  const float* as1  = (const float*)d_in[4];
  const float* ad1  = (const float*)d_in[5];
  const float* b1   = (const float*)d_in[6];
  const float* W2   = (const float*)d_in[7];
  const float* as2  = (const float*)d_in[8];
  const float* ad2  = (const float*)d_in[9];
  const float* b2   = (const float*)d_in[10];
  const float* Wg   = (const float*)d_in[11];
  const float* bg   = (const float*)d_in[12];
  const float* Wc1  = (const float*)d_in[13];
  const float* bc1  = (const float*)d_in[14];
  const float* Wc2  = (const float*)d_in[15];
  const float* bc2  = (const float*)d_in[16];

  char* ws = (char*)d_ws;
  unsigned short* x2s   = (unsigned short*)(ws + 0LL);         // [N][512] bf16 split
  unsigned short* out1s = (unsigned short*)(ws + 0LL);         // same region (x2 dead after gemm1)
  __half* h1h   = (__half*)(ws + 51200000LL);   // [N][256] fp16 = 25.6MB
  __half* t2h   = (__half*)(ws + 102400000LL);  // [N][64] fp16 = 6.4MB
  float* hf     = (float*)(ws + 115200000LL);   // 12.8MB (written late by k_agg2w)
  float* P      = (float*)(ws + 115200000LL);   // 8KB (dead before hf written)
  unsigned short* W1B3t = (unsigned short*)(ws + 115208192LL); // 393216B
  unsigned short* W2B3t = (unsigned short*)(ws + 115601408LL); // 98304B
  float* asrc1  = (float*)(ws + 128000000LL);   // 800KB
  float* adst1  = (float*)(ws + 128800000LL);   // 800KB
  float* asrc2  = (float*)(ws + 129600000LL);   // 200KB
  float* adst2  = (float*)(ws + 129800000LL);   // 200KB
  float* attg   = (float*)(ws + 130000000LL);   // 200KB
  int*   deg    = (int*)  (ws + 130200000LL);   // 200KB
  int*   fill   = (int*)  (ws + 130400000LL);   // 200KB
  int*   row_st = (int*)  (ws + 130600256LL);   // 200KB
  int*   col    = (int*)  (ws + 130800256LL);   // 3.4MB
  float* outf   = (float*)d_out;

  hipMemsetAsync(ws + 130200000LL, 0, 400256, stream);

  // K1: count + W-splits + P projection (all independent)
  k_prepc<<<NB_COUNT + 322, 256, 0, stream>>>(ei, W1, W2, as1, ad1, deg, W1B3t, W2B3t, P);
  // K2: CSR scan (block 0, starts first) + att1 scalars + x split
  k_att1s<<<12501, 256, 0, stream>>>(x, P, asrc1, adst1, x2s, deg, row_st);
  // K3: gemm1 (needs x2s, W1B3t) + CSR fill (needs row_st)
  k_fg1<<<782 + NB_COUNT, 256, 0, stream>>>(x2s, W1B3t, h1h, ei, row_st, fill, col);
  // K4
  k_agg1w<<<N_NODES / 4, 256, 0, stream>>>(h1h, col, row_st, deg, asrc1, adst1, b1, out1s);
  // K5
  mfma_gemm<64, 1><<<dim3(1, 391), 256, 0, stream>>>(out1s, W2B3t, (void*)t2h, N_NODES, 64);
  // K6
  k_att2<<<N_NODES / 4, 256, 0, stream>>>(t2h, as2, ad2, asrc2, adst2);
  // K7
  k_agg2w<<<N_NODES / 4, 256, 0, stream>>>(t2h, col, row_st, deg, asrc2, adst2, b2, Wg, bg, hf, attg);
  // K8
  k_pool<<<NGRAPH, 256, 0, stream>>>(hf, attg, batch, Wc1, bc1, Wc2, bc2, outf);
}